// Round 3
// baseline (273.410 us; speedup 1.0000x reference)
//
#include <hip/hip_runtime.h>

#define A_N 8400
#define B_N 32
#define NGT 64
#define NC  80
#define BA  (B_N * A_N)
#define NCOL (B_N * NGT)

// ---------------------------------------------------------------------------
// Init: zero fg_mask + per-column counters, init per-batch min/max.
// ---------------------------------------------------------------------------
__global__ __launch_bounds__(256) void k_init_all(int* __restrict__ fg,
                                                  int* __restrict__ cnts,
                                                  unsigned* __restrict__ mn_g,
                                                  unsigned* __restrict__ mx_g) {
  int idx = blockIdx.x * 256 + threadIdx.x;
  if (idx < BA) fg[idx] = 0;
  if (idx < NCOL) cnts[idx] = 0;
  if (idx < B_N) {
    mn_g[idx] = __float_as_uint(1e30f);
    mx_g[idx] = 0u;  // +0.0f bits; am_max >= 0 always
  }
}

// ---------------------------------------------------------------------------
// Pass 1: per (b, anchor). For each valid gt: cheap in_gts test; full amf
// (bit-identical to ref: fp contract off, powf/sqrtf order preserved --
// verified absmax 0.0 in rounds 1-2) only when in_gts. amf>0 pairs are pushed
// to the per-column list (key = value_bits<<32 | ~a: max key == max value,
// tie -> min anchor; all amf >= +0.0 so uint order == float order).
// Row argmax (first-max == jnp.argmax, zeros exact for !in_gts) inline.
// ---------------------------------------------------------------------------
__global__ __launch_bounds__(256) void k_sparse_row(
    const float* __restrict__ pd_s, const float* __restrict__ pd_b,
    const float* __restrict__ anc, const int* __restrict__ gt_l,
    const float* __restrict__ gt_b, const int* __restrict__ mgt,
    unsigned long long* __restrict__ lists, int* __restrict__ cnts, int cap,
    int* __restrict__ gt_idx, float* __restrict__ am_max_g) {
#pragma clang fp contract(off)
  int b = blockIdx.y;
  int tid = threadIdx.x;
  int a = blockIdx.x * 256 + tid;

  __shared__ float4 gb_s[NGT];
  __shared__ int lab_s[NGT];
  __shared__ int cnt_s;
  if (tid < NGT) {
    gb_s[tid] = ((const float4*)gt_b)[b * NGT + tid];
    lab_s[tid] = gt_l[b * NGT + tid];
    int v = mgt[b * NGT + tid];
    unsigned long long m = __ballot(v != 0);  // mask_gt is a prefix mask
    if (tid == 0) cnt_s = __popcll(m);
  }
  __syncthreads();
  int cnt = cnt_s;
  if (a >= A_N) return;

  float4 pb = ((const float4*)pd_b)[(size_t)b * A_N + a];
  float2 ap = ((const float2*)anc)[a];
  size_t row = ((size_t)b * A_N + a) * NC;

  float best = -3.0e38f;
  int bi = 0;
  for (int n = 0; n < cnt; n++) {
    float4 gb = gb_s[n];
    float mn = fminf(fminf(ap.x - gb.x, ap.y - gb.y),
                     fminf(gb.z - ap.x, gb.w - ap.y));
    float v = 0.0f;  // align * in_gts == +0.0 exactly when !in_gts
    if (mn > 0.0f) {
      float iw = fmaxf(fminf(gb.z, pb.z) - fmaxf(gb.x, pb.x), 0.0f);
      float ih = fmaxf(fminf(gb.w, pb.w) - fmaxf(gb.y, pb.y), 0.0f);
      float inter = iw * ih;
      float w1 = gb.z - gb.x, h1 = (gb.w - gb.y) + 1e-16f;
      float w2 = pb.z - pb.x, h2 = (pb.w - pb.y) + 1e-16f;
      float uni = ((w1 * h1 + w2 * h2) - inter) + 1e-16f;
      float iou = inter / uni;
      float sc = pd_s[row + (size_t)lab_s[n]];
      v = sqrtf(sc) * powf(iou, 6.0f);
    }
    if (v > best) { best = v; bi = n; }
    if (v > 0.0f) {
      int col = b * NGT + n;
      int pos = atomicAdd(&cnts[col], 1);
      if (pos < cap) {
        unsigned long long key =
            ((unsigned long long)__float_as_uint(v) << 32) |
            (unsigned long long)(0xFFFFFFFFu - (unsigned)a);
        lists[(size_t)col * cap + pos] = key;
      }
    }
  }
  size_t i = (size_t)b * A_N + a;
  gt_idx[i] = bi;
  am_max_g[i] = fmaxf(best, 0.0f);
}

// ---------------------------------------------------------------------------
// Pass 2: per (b, gt) column, one wave. Winners = top-10 by (v desc, a asc)
// over the FULL 8400 column. Positives come from the list; if P < 10, the
// remaining winners are the (10-P) smallest-index zero-valued anchors (every
// zero candidate consumes a top-k slot; only in_gts ones become fg --
// jax.lax.top_k stable tie-break semantics). Winners set fg and fold the
// per-batch min/max of am_max directly (idempotent atomics).
// ---------------------------------------------------------------------------
__global__ __launch_bounds__(64) void k_topk_sparse(
    const unsigned long long* __restrict__ lists, const int* __restrict__ cnts,
    int cap, const int* __restrict__ mgt, const float* __restrict__ anc,
    const float* __restrict__ gt_b, const float* __restrict__ am_max_g,
    int* __restrict__ fg_mask, unsigned* __restrict__ mn_g,
    unsigned* __restrict__ mx_g) {
  int b = blockIdx.x, n = blockIdx.y, tid = threadIdx.x;
  if (mgt[b * NGT + n] == 0) return;
  int col = b * NGT + n;
  int P = cnts[col];
  if (P > cap) P = cap;
  const unsigned long long* list = lists + (size_t)col * cap;

  if (P >= 10) {
    // All 10 winners are positive => in_gts guaranteed.
    unsigned long long top[10];
#pragma unroll
    for (int j = 0; j < 10; j++) top[j] = 0ull;
    for (int i = tid; i < P; i += 64) {
      unsigned long long key = list[i];
#pragma unroll
      for (int j = 0; j < 10; j++) {
        if (key > top[j]) { unsigned long long t = top[j]; top[j] = key; key = t; }
      }
    }
    for (int r = 0; r < 10; r++) {
      unsigned long long g = top[0];
#pragma unroll
      for (int off = 32; off >= 1; off >>= 1) {
        unsigned long long o = __shfl_xor(g, off, 64);
        g = (o > g) ? o : g;
      }
      // all lanes hold g; unique keys -> exactly one lane pops
      if (top[0] == g) {
#pragma unroll
        for (int j = 0; j < 9; j++) top[j] = top[j + 1];
        top[9] = 0ull;
      }
      if (tid == r) {
        int a = (int)(0xFFFFFFFFu - (unsigned)(g & 0xFFFFFFFFull));
        atomicOr(&fg_mask[(size_t)b * A_N + a], 1);
        unsigned u = __float_as_uint(am_max_g[(size_t)b * A_N + a]);
        atomicMin(&mn_g[b], u);
        atomicMax(&mx_g[b], u);
      }
    }
  } else if (tid == 0) {
    // P < 10: positives all win; then walk smallest-index zero-valued anchors.
    int pos_a[9];
    for (int i = 0; i < P; i++) {
      int a = (int)(0xFFFFFFFFu - (unsigned)(list[i] & 0xFFFFFFFFull));
      pos_a[i] = a;
      atomicOr(&fg_mask[(size_t)b * A_N + a], 1);
      unsigned u = __float_as_uint(am_max_g[(size_t)b * A_N + a]);
      atomicMin(&mn_g[b], u);
      atomicMax(&mx_g[b], u);
    }
    float4 gb = ((const float4*)gt_b)[b * NGT + n];
    int need = 10 - P;
    int a = 0;
    while (need > 0 && a < A_N) {
      bool is_pos = false;
      for (int i = 0; i < P; i++) is_pos |= (pos_a[i] == a);
      if (!is_pos) {
        // zero-valued winner: consumes a slot regardless; fg only if in_gts
        float2 ap = ((const float2*)anc)[a];
        float mn = fminf(fminf(ap.x - gb.x, ap.y - gb.y),
                         fminf(gb.z - ap.x, gb.w - ap.y));
        if (mn > 0.0f) {
          atomicOr(&fg_mask[(size_t)b * A_N + a], 1);
          unsigned u = __float_as_uint(am_max_g[(size_t)b * A_N + a]);
          atomicMin(&mn_g[b], u);
          atomicMax(&mx_g[b], u);
        }
        need--;
      }
      a++;
    }
  }
}

// ---------------------------------------------------------------------------
// Output: t_labels, t_bboxes, fg per anchor; then the 80-class score block
// written contiguously (80 KB / block, coalesced float4) from LDS-staged
// cls/norm.
// ---------------------------------------------------------------------------
__global__ __launch_bounds__(256) void k_out_fused(
    const int* __restrict__ gt_l, const float* __restrict__ gt_b,
    const int* __restrict__ fg_mask, const int* __restrict__ gt_idx,
    const float* __restrict__ am_max_g, const unsigned* __restrict__ mn_g,
    const unsigned* __restrict__ mx_g, float* __restrict__ out) {
  int b = blockIdx.y;
  int tid = threadIdx.x;
  int a0 = blockIdx.x * 256;
  int a = a0 + tid;

  __shared__ int cls_s[256];
  __shared__ float norm_s[256];

  if (a < A_N) {
    size_t i = (size_t)b * A_N + a;
    bool fg = fg_mask[i] != 0;
    int bi = gt_idx[i];
    float amx = am_max_g[i];
    float mn = __uint_as_float(mn_g[b]);
    float mx = __uint_as_float(mx_g[b]);
    float norm = (amx - mn) / ((mx - mn) + 1e-9f);
    int lab = gt_l[b * NGT + bi];

    out[i] = fg ? (float)lab : (float)NC;  // t_labels
    float4 bb = fg ? ((const float4*)gt_b)[b * NGT + bi]
                   : make_float4(0.f, 0.f, 0.f, 0.f);
    ((float4*)(out + BA))[i] = bb;               // t_bboxes
    out[(size_t)85 * BA + i] = fg ? 1.0f : 0.0f; // fg
    cls_s[tid] = fg ? lab : -1;
    norm_s[tid] = fg ? norm : 0.0f;
  } else {
    cls_s[tid] = -1;
    norm_s[tid] = 0.0f;
  }
  __syncthreads();

  int nA = A_N - a0;
  if (nA > 256) nA = 256;
  float4* dst = (float4*)(out + (size_t)5 * BA + ((size_t)b * A_N + a0) * NC);
  int nvec = nA * (NC / 4);
  for (int t = tid; t < nvec; t += 256) {
    int al = t / (NC / 4);
    int c0 = (t - al * (NC / 4)) * 4;
    int cls = cls_s[al];
    float nv = norm_s[al];
    float4 r;
    r.x = (c0 == cls) ? nv : 0.0f;
    r.y = (c0 + 1 == cls) ? nv : 0.0f;
    r.z = (c0 + 2 == cls) ? nv : 0.0f;
    r.w = (c0 + 3 == cls) ? nv : 0.0f;
    dst[t] = r;
  }
}

extern "C" void kernel_launch(void* const* d_in, const int* in_sizes, int n_in,
                              void* d_out, int out_size, void* d_ws,
                              size_t ws_size, hipStream_t stream) {
  const float* pd_s = (const float*)d_in[0];   // (B, A, 80)
  const float* pd_b = (const float*)d_in[1];   // (B, A, 4)
  const float* anc  = (const float*)d_in[2];   // (A, 2)
  const int*   gt_l = (const int*)d_in[3];     // (B, 64, 1)
  const float* gt_b = (const float*)d_in[4];   // (B, 64, 4)
  const int*   mgt  = (const int*)d_in[5];     // (B, 64, 1)

  float* out = (float*)d_out;
  char* ws = (char*)d_ws;

  // Small buffers at the end; per-column lists take the rest (cap per column).
  const size_t SMALL = (size_t)BA * 4;
  size_t small_bytes = 3 * SMALL + (size_t)NCOL * 4 + 256;
  size_t avail = (ws_size > small_bytes) ? (ws_size - small_bytes) : 0;
  int cap = (int)(avail / ((size_t)NCOL * 8));
  if (cap > 4096) cap = 4096;  // max in_gts anchors/col is ~800 with this data
  if (cap < 1) cap = 1;

  unsigned long long* lists = (unsigned long long*)ws;
  char* sb = ws + (size_t)NCOL * 8 * cap;
  int*      fg_mask  = (int*)sb;
  int*      gt_idx   = (int*)(sb + SMALL);
  float*    am_max_g = (float*)(sb + 2 * SMALL);
  int*      cnts     = (int*)(sb + 3 * SMALL);
  unsigned* mn_g     = (unsigned*)(sb + 3 * SMALL + (size_t)NCOL * 4);
  unsigned* mx_g     = mn_g + B_N;

  dim3 g2((A_N + 255) / 256, B_N);
  k_init_all<<<(BA + 255) / 256, 256, 0, stream>>>(fg_mask, cnts, mn_g, mx_g);
  k_sparse_row<<<g2, 256, 0, stream>>>(pd_s, pd_b, anc, gt_l, gt_b, mgt, lists,
                                       cnts, cap, gt_idx, am_max_g);
  k_topk_sparse<<<dim3(B_N, NGT), 64, 0, stream>>>(lists, cnts, cap, mgt, anc,
                                                   gt_b, am_max_g, fg_mask,
                                                   mn_g, mx_g);
  k_out_fused<<<g2, 256, 0, stream>>>(gt_l, gt_b, fg_mask, gt_idx, am_max_g,
                                      mn_g, mx_g, out);
}

// Round 4
// 228.909 us; speedup vs baseline: 1.1944x; 1.1944x over previous
//
#include <hip/hip_runtime.h>

#define A_N 8400
#define B_N 32
#define NGT 64
#define NC  80
#define BA  (B_N * A_N)
#define NCOL (B_N * NGT)

// ---------------------------------------------------------------------------
// Init: zero fg_mask + per-column counters, init per-batch min/max.
// ---------------------------------------------------------------------------
__global__ __launch_bounds__(256) void k_init_all(int* __restrict__ fg,
                                                  int* __restrict__ cnts,
                                                  unsigned* __restrict__ mn_g,
                                                  unsigned* __restrict__ mx_g) {
  int idx = blockIdx.x * 256 + threadIdx.x;
  if (idx < BA) fg[idx] = 0;
  if (idx < NCOL) cnts[idx] = 0;
  if (idx < B_N) {
    mn_g[idx] = __float_as_uint(1e30f);
    mx_g[idx] = 0u;  // +0.0f bits; am_max >= 0 always
  }
}

// ---------------------------------------------------------------------------
// Pass 1 (restructured round 4): block = 256 anchors of one batch.
// Phase 1: branch-light in-box tests (cheap, full lanes) push (anchor,gt)
//          pairs into an LDS worklist, 32-gt chunks (worklist cap 256*32).
// Phase 2: cooperative drain -- each worklist item is one independent
//          scattered pd_s load (all in flight -> one latency, not 20 serial)
//          + amf arithmetic at full lane utilization. Results: global
//          per-column candidate lists + per-anchor argmax via LDS atomicMax
//          on key (vbits<<32 | 63-n)  == first-max argmax (max v, tie min n).
// Phase 3: decode per-anchor key -> gt_idx, am_max.
// amf expression is bit-identical to rounds 1-3 (contract off, powf order
// preserved -- verified absmax 0.0). Zeros for !in_gts are exact (+0.0).
// ---------------------------------------------------------------------------
__global__ __launch_bounds__(256) void k_pairs(
    const float* __restrict__ pd_s, const float* __restrict__ pd_b,
    const float* __restrict__ anc, const int* __restrict__ gt_l,
    const float* __restrict__ gt_b, const int* __restrict__ mgt,
    unsigned long long* __restrict__ lists, int* __restrict__ cnts, int cap,
    int* __restrict__ gt_idx, float* __restrict__ am_max_g) {
#pragma clang fp contract(off)
  int b = blockIdx.y, tid = threadIdx.x;
  int a0 = blockIdx.x * 256, a = a0 + tid;
  bool av = a < A_N;

  __shared__ float4 gb_s[NGT];
  __shared__ int lab_s[NGT];
  __shared__ float4 pb_s[256];
  __shared__ float2 ap_s[256];
  __shared__ unsigned long long key_s[256];
  __shared__ unsigned short wl[256 * 32];  // 16 KB, exact worst case per chunk
  __shared__ int wl_cnt;
  __shared__ int cnt_sh;

  if (tid < NGT) {
    gb_s[tid] = ((const float4*)gt_b)[b * NGT + tid];
    lab_s[tid] = gt_l[b * NGT + tid];
    unsigned long long m = __ballot(mgt[b * NGT + tid] != 0);  // prefix mask
    if (tid == 0) cnt_sh = __popcll(m);
  }
  pb_s[tid] = av ? ((const float4*)pd_b)[(size_t)b * A_N + a]
                 : make_float4(0.f, 0.f, 0.f, 0.f);
  ap_s[tid] = av ? ((const float2*)anc)[a] : make_float2(-1e30f, -1e30f);
  key_s[tid] = 63ull;  // (v=0, n=0): default argmax when no positive pair
  if (tid == 0) wl_cnt = 0;
  __syncthreads();
  int cnt = cnt_sh;
  float2 ap = ap_s[tid];

  for (int g0 = 0; g0 < cnt; g0 += 32) {
    int ge = (g0 + 32 < cnt) ? g0 + 32 : cnt;
    // phase 1: in-box test + push (pairs are rare, ~2%)
    if (av) {
      for (int n = g0; n < ge; n++) {
        float4 gb = gb_s[n];
        float mn = fminf(fminf(ap.x - gb.x, ap.y - gb.y),
                         fminf(gb.z - ap.x, gb.w - ap.y));
        if (mn > 0.0f) {
          int p = atomicAdd(&wl_cnt, 1);
          wl[p] = (unsigned short)((tid << 6) | (n & 63));
        }
      }
    }
    __syncthreads();
    int m = wl_cnt;
    // phase 2: cooperative drain -- independent scattered loads, full MLP
    for (int i = tid; i < m; i += 256) {
      int e = wl[i];
      int al = e >> 6, n = e & 63;
      int ag = a0 + al;
      float4 gb = gb_s[n];
      float4 pb = pb_s[al];
      float iw = fmaxf(fminf(gb.z, pb.z) - fmaxf(gb.x, pb.x), 0.0f);
      float ih = fmaxf(fminf(gb.w, pb.w) - fmaxf(gb.y, pb.y), 0.0f);
      float inter = iw * ih;
      float w1 = gb.z - gb.x, h1 = (gb.w - gb.y) + 1e-16f;
      float w2 = pb.z - pb.x, h2 = (pb.w - pb.y) + 1e-16f;
      float uni = ((w1 * h1 + w2 * h2) - inter) + 1e-16f;
      float iou = inter / uni;
      float sc = pd_s[((size_t)b * A_N + ag) * NC + (size_t)lab_s[n]];
      float v = sqrtf(sc) * powf(iou, 6.0f);
      if (v > 0.0f) {
        unsigned vb = __float_as_uint(v);
        int col = b * NGT + n;
        int pos = atomicAdd(&cnts[col], 1);
        if (pos < cap) {
          lists[(size_t)col * cap + pos] =
              ((unsigned long long)vb << 32) |
              (unsigned long long)(0xFFFFFFFFu - (unsigned)ag);
        }
        atomicMax(&key_s[al],
                  ((unsigned long long)vb << 32) | (unsigned long long)(63 - n));
      }
    }
    __syncthreads();
    if (tid == 0) wl_cnt = 0;
    __syncthreads();
  }

  if (av) {
    unsigned long long k = key_s[tid];
    size_t i = (size_t)b * A_N + a;
    gt_idx[i] = 63 - (int)(k & 63ull);
    am_max_g[i] = __uint_as_float((unsigned)(k >> 32));
  }
}

// ---------------------------------------------------------------------------
// Pass 2: per (b, gt) column, one wave. Winners = top-10 by (v desc, a asc)
// over the FULL 8400 column. Positives come from the list; if P < 10, the
// remaining winners are the (10-P) smallest-index zero-valued anchors (every
// zero candidate consumes a top-k slot; only in_gts ones become fg --
// jax.lax.top_k stable tie-break semantics). Winners set fg and fold the
// per-batch min/max of am_max directly (idempotent atomics).
// ---------------------------------------------------------------------------
__global__ __launch_bounds__(64) void k_topk_sparse(
    const unsigned long long* __restrict__ lists, const int* __restrict__ cnts,
    int cap, const int* __restrict__ mgt, const float* __restrict__ anc,
    const float* __restrict__ gt_b, const float* __restrict__ am_max_g,
    int* __restrict__ fg_mask, unsigned* __restrict__ mn_g,
    unsigned* __restrict__ mx_g) {
  int b = blockIdx.x, n = blockIdx.y, tid = threadIdx.x;
  if (mgt[b * NGT + n] == 0) return;
  int col = b * NGT + n;
  int P = cnts[col];
  if (P > cap) P = cap;
  const unsigned long long* list = lists + (size_t)col * cap;

  if (P >= 10) {
    // All 10 winners are positive => in_gts guaranteed.
    unsigned long long top[10];
#pragma unroll
    for (int j = 0; j < 10; j++) top[j] = 0ull;
    for (int i = tid; i < P; i += 64) {
      unsigned long long key = list[i];
#pragma unroll
      for (int j = 0; j < 10; j++) {
        if (key > top[j]) { unsigned long long t = top[j]; top[j] = key; key = t; }
      }
    }
    for (int r = 0; r < 10; r++) {
      unsigned long long g = top[0];
#pragma unroll
      for (int off = 32; off >= 1; off >>= 1) {
        unsigned long long o = __shfl_xor(g, off, 64);
        g = (o > g) ? o : g;
      }
      // all lanes hold g; unique keys -> exactly one lane pops
      if (top[0] == g) {
#pragma unroll
        for (int j = 0; j < 9; j++) top[j] = top[j + 1];
        top[9] = 0ull;
      }
      if (tid == r) {
        int a = (int)(0xFFFFFFFFu - (unsigned)(g & 0xFFFFFFFFull));
        atomicOr(&fg_mask[(size_t)b * A_N + a], 1);
        unsigned u = __float_as_uint(am_max_g[(size_t)b * A_N + a]);
        atomicMin(&mn_g[b], u);
        atomicMax(&mx_g[b], u);
      }
    }
  } else if (tid == 0) {
    // P < 10: positives all win; then walk smallest-index zero-valued anchors.
    int pos_a[9];
    for (int i = 0; i < P; i++) {
      int a = (int)(0xFFFFFFFFu - (unsigned)(list[i] & 0xFFFFFFFFull));
      pos_a[i] = a;
      atomicOr(&fg_mask[(size_t)b * A_N + a], 1);
      unsigned u = __float_as_uint(am_max_g[(size_t)b * A_N + a]);
      atomicMin(&mn_g[b], u);
      atomicMax(&mx_g[b], u);
    }
    float4 gb = ((const float4*)gt_b)[b * NGT + n];
    int need = 10 - P;
    int a = 0;
    while (need > 0 && a < A_N) {
      bool is_pos = false;
      for (int i = 0; i < P; i++) is_pos |= (pos_a[i] == a);
      if (!is_pos) {
        // zero-valued winner: consumes a slot regardless; fg only if in_gts
        float2 ap = ((const float2*)anc)[a];
        float mn = fminf(fminf(ap.x - gb.x, ap.y - gb.y),
                         fminf(gb.z - ap.x, gb.w - ap.y));
        if (mn > 0.0f) {
          atomicOr(&fg_mask[(size_t)b * A_N + a], 1);
          unsigned u = __float_as_uint(am_max_g[(size_t)b * A_N + a]);
          atomicMin(&mn_g[b], u);
          atomicMax(&mx_g[b], u);
        }
        need--;
      }
      a++;
    }
  }
}

// ---------------------------------------------------------------------------
// Output: t_labels, t_bboxes, fg per anchor; then the 80-class score block
// written contiguously (80 KB / block, coalesced float4) from LDS-staged
// cls/norm.
// ---------------------------------------------------------------------------
__global__ __launch_bounds__(256) void k_out_fused(
    const int* __restrict__ gt_l, const float* __restrict__ gt_b,
    const int* __restrict__ fg_mask, const int* __restrict__ gt_idx,
    const float* __restrict__ am_max_g, const unsigned* __restrict__ mn_g,
    const unsigned* __restrict__ mx_g, float* __restrict__ out) {
  int b = blockIdx.y;
  int tid = threadIdx.x;
  int a0 = blockIdx.x * 256;
  int a = a0 + tid;

  __shared__ int cls_s[256];
  __shared__ float norm_s[256];

  if (a < A_N) {
    size_t i = (size_t)b * A_N + a;
    bool fg = fg_mask[i] != 0;
    int bi = gt_idx[i];
    float amx = am_max_g[i];
    float mn = __uint_as_float(mn_g[b]);
    float mx = __uint_as_float(mx_g[b]);
    float norm = (amx - mn) / ((mx - mn) + 1e-9f);
    int lab = gt_l[b * NGT + bi];

    out[i] = fg ? (float)lab : (float)NC;  // t_labels
    float4 bb = fg ? ((const float4*)gt_b)[b * NGT + bi]
                   : make_float4(0.f, 0.f, 0.f, 0.f);
    ((float4*)(out + BA))[i] = bb;               // t_bboxes
    out[(size_t)85 * BA + i] = fg ? 1.0f : 0.0f; // fg
    cls_s[tid] = fg ? lab : -1;
    norm_s[tid] = fg ? norm : 0.0f;
  } else {
    cls_s[tid] = -1;
    norm_s[tid] = 0.0f;
  }
  __syncthreads();

  int nA = A_N - a0;
  if (nA > 256) nA = 256;
  float4* dst = (float4*)(out + (size_t)5 * BA + ((size_t)b * A_N + a0) * NC);
  int nvec = nA * (NC / 4);
  for (int t = tid; t < nvec; t += 256) {
    int al = t / (NC / 4);
    int c0 = (t - al * (NC / 4)) * 4;
    int cls = cls_s[al];
    float nv = norm_s[al];
    float4 r;
    r.x = (c0 == cls) ? nv : 0.0f;
    r.y = (c0 + 1 == cls) ? nv : 0.0f;
    r.z = (c0 + 2 == cls) ? nv : 0.0f;
    r.w = (c0 + 3 == cls) ? nv : 0.0f;
    dst[t] = r;
  }
}

extern "C" void kernel_launch(void* const* d_in, const int* in_sizes, int n_in,
                              void* d_out, int out_size, void* d_ws,
                              size_t ws_size, hipStream_t stream) {
  const float* pd_s = (const float*)d_in[0];   // (B, A, 80)
  const float* pd_b = (const float*)d_in[1];   // (B, A, 4)
  const float* anc  = (const float*)d_in[2];   // (A, 2)
  const int*   gt_l = (const int*)d_in[3];     // (B, 64, 1)
  const float* gt_b = (const float*)d_in[4];   // (B, 64, 4)
  const int*   mgt  = (const int*)d_in[5];     // (B, 64, 1)

  float* out = (float*)d_out;
  char* ws = (char*)d_ws;

  // Small buffers at the end; per-column lists take the rest (cap per column).
  const size_t SMALL = (size_t)BA * 4;
  size_t small_bytes = 3 * SMALL + (size_t)NCOL * 4 + 256;
  size_t avail = (ws_size > small_bytes) ? (ws_size - small_bytes) : 0;
  int cap = (int)(avail / ((size_t)NCOL * 8));
  if (cap > 4096) cap = 4096;  // max in_gts anchors/col is ~800 with this data
  if (cap < 1) cap = 1;

  unsigned long long* lists = (unsigned long long*)ws;
  char* sb = ws + (size_t)NCOL * 8 * cap;
  int*      fg_mask  = (int*)sb;
  int*      gt_idx   = (int*)(sb + SMALL);
  float*    am_max_g = (float*)(sb + 2 * SMALL);
  int*      cnts     = (int*)(sb + 3 * SMALL);
  unsigned* mn_g     = (unsigned*)(sb + 3 * SMALL + (size_t)NCOL * 4);
  unsigned* mx_g     = mn_g + B_N;

  dim3 g2((A_N + 255) / 256, B_N);
  k_init_all<<<(BA + 255) / 256, 256, 0, stream>>>(fg_mask, cnts, mn_g, mx_g);
  k_pairs<<<g2, 256, 0, stream>>>(pd_s, pd_b, anc, gt_l, gt_b, mgt, lists,
                                  cnts, cap, gt_idx, am_max_g);
  k_topk_sparse<<<dim3(B_N, NGT), 64, 0, stream>>>(lists, cnts, cap, mgt, anc,
                                                   gt_b, am_max_g, fg_mask,
                                                   mn_g, mx_g);
  k_out_fused<<<g2, 256, 0, stream>>>(gt_l, gt_b, fg_mask, gt_idx, am_max_g,
                                      mn_g, mx_g, out);
}

// Round 5
// 184.607 us; speedup vs baseline: 1.4810x; 1.2400x over previous
//
#include <hip/hip_runtime.h>

#define A_N 8400
#define B_N 32
#define NGT 64
#define NC  80
#define BA  (B_N * A_N)
#define NCOL (B_N * NGT)

// ---------------------------------------------------------------------------
// Init: zero fg_mask + per-column counters, init per-batch min/max.
// ---------------------------------------------------------------------------
__global__ __launch_bounds__(256) void k_init_all(int* __restrict__ fg,
                                                  int* __restrict__ cnts,
                                                  unsigned* __restrict__ mn_g,
                                                  unsigned* __restrict__ mx_g) {
  int idx = blockIdx.x * 256 + threadIdx.x;
  if (idx < BA) fg[idx] = 0;
  if (idx < NCOL) cnts[idx] = 0;
  if (idx < B_N) {
    mn_g[idx] = __float_as_uint(1e30f);
    mx_g[idx] = 0u;  // +0.0f bits; am_max >= 0 always
  }
}

// ---------------------------------------------------------------------------
// Pass 1: block = 256 anchors of one batch. In-box tests push (anchor,gt)
// pairs to an LDS worklist; cooperative drain computes amf with full memory-
// level parallelism. Results: per-column candidate lists + per-anchor argmax
// via LDS atomicMax on key (vbits<<32 | 63-n) == first-max argmax.
// amf expression bit-identical to rounds 1-4 (verified absmax 0.0).
// ---------------------------------------------------------------------------
__global__ __launch_bounds__(256) void k_pairs(
    const float* __restrict__ pd_s, const float* __restrict__ pd_b,
    const float* __restrict__ anc, const int* __restrict__ gt_l,
    const float* __restrict__ gt_b, const int* __restrict__ mgt,
    unsigned long long* __restrict__ lists, int* __restrict__ cnts, int cap,
    int* __restrict__ gt_idx, float* __restrict__ am_max_g) {
#pragma clang fp contract(off)
  int b = blockIdx.y, tid = threadIdx.x;
  int a0 = blockIdx.x * 256, a = a0 + tid;
  bool av = a < A_N;

  __shared__ float4 gb_s[NGT];
  __shared__ int lab_s[NGT];
  __shared__ float4 pb_s[256];
  __shared__ float2 ap_s[256];
  __shared__ unsigned long long key_s[256];
  __shared__ unsigned short wl[256 * 32];  // 16 KB, exact worst case per chunk
  __shared__ int wl_cnt;
  __shared__ int cnt_sh;

  if (tid < NGT) {
    gb_s[tid] = ((const float4*)gt_b)[b * NGT + tid];
    lab_s[tid] = gt_l[b * NGT + tid];
    unsigned long long m = __ballot(mgt[b * NGT + tid] != 0);  // prefix mask
    if (tid == 0) cnt_sh = __popcll(m);
  }
  pb_s[tid] = av ? ((const float4*)pd_b)[(size_t)b * A_N + a]
                 : make_float4(0.f, 0.f, 0.f, 0.f);
  ap_s[tid] = av ? ((const float2*)anc)[a] : make_float2(-1e30f, -1e30f);
  key_s[tid] = 63ull;  // (v=0, n=0): default argmax when no positive pair
  if (tid == 0) wl_cnt = 0;
  __syncthreads();
  int cnt = cnt_sh;
  float2 ap = ap_s[tid];

  for (int g0 = 0; g0 < cnt; g0 += 32) {
    int ge = (g0 + 32 < cnt) ? g0 + 32 : cnt;
    // phase 1: in-box test + push (pairs are rare, ~2%)
    if (av) {
      for (int n = g0; n < ge; n++) {
        float4 gb = gb_s[n];
        float mn = fminf(fminf(ap.x - gb.x, ap.y - gb.y),
                         fminf(gb.z - ap.x, gb.w - ap.y));
        if (mn > 0.0f) {
          int p = atomicAdd(&wl_cnt, 1);
          wl[p] = (unsigned short)((tid << 6) | (n & 63));
        }
      }
    }
    __syncthreads();
    int m = wl_cnt;
    // phase 2: cooperative drain -- independent scattered loads, full MLP
    for (int i = tid; i < m; i += 256) {
      int e = wl[i];
      int al = e >> 6, n = e & 63;
      int ag = a0 + al;
      float4 gb = gb_s[n];
      float4 pb = pb_s[al];
      float iw = fmaxf(fminf(gb.z, pb.z) - fmaxf(gb.x, pb.x), 0.0f);
      float ih = fmaxf(fminf(gb.w, pb.w) - fmaxf(gb.y, pb.y), 0.0f);
      float inter = iw * ih;
      float w1 = gb.z - gb.x, h1 = (gb.w - gb.y) + 1e-16f;
      float w2 = pb.z - pb.x, h2 = (pb.w - pb.y) + 1e-16f;
      float uni = ((w1 * h1 + w2 * h2) - inter) + 1e-16f;
      float iou = inter / uni;
      float sc = pd_s[((size_t)b * A_N + ag) * NC + (size_t)lab_s[n]];
      float v = sqrtf(sc) * powf(iou, 6.0f);
      if (v > 0.0f) {
        unsigned vb = __float_as_uint(v);
        int col = b * NGT + n;
        int pos = atomicAdd(&cnts[col], 1);
        if (pos < cap) {
          lists[(size_t)col * cap + pos] =
              ((unsigned long long)vb << 32) |
              (unsigned long long)(0xFFFFFFFFu - (unsigned)ag);
        }
        atomicMax(&key_s[al],
                  ((unsigned long long)vb << 32) | (unsigned long long)(63 - n));
      }
    }
    __syncthreads();
    if (tid == 0) wl_cnt = 0;
    __syncthreads();
  }

  if (av) {
    unsigned long long k = key_s[tid];
    size_t i = (size_t)b * A_N + a;
    gt_idx[i] = 63 - (int)(k & 63ull);
    am_max_g[i] = __uint_as_float((unsigned)(k >> 32));
  }
}

// ---------------------------------------------------------------------------
// Pass 2: per (b, gt) column, one wave. Winners = top-10 by (v desc, a asc)
// over the FULL 8400 column (positives from the list; if P < 10, the
// remaining winners are the smallest-index zero-valued anchors; only in_gts
// ones become fg -- jax.lax.top_k stable tie-break semantics).
// ROUND 5: per-batch min/max folded BLOCK-LOCALLY first -> exactly one
// atomicMin + one atomicMax per block (was up to 10 pairs/block; 40k RMWs on
// 2 cache lines serialized at the TCC ~= the whole 59 us of round 4).
// ---------------------------------------------------------------------------
__global__ __launch_bounds__(64) void k_topk_sparse(
    const unsigned long long* __restrict__ lists, const int* __restrict__ cnts,
    int cap, const int* __restrict__ mgt, const float* __restrict__ anc,
    const float* __restrict__ gt_b, const float* __restrict__ am_max_g,
    int* __restrict__ fg_mask, unsigned* __restrict__ mn_g,
    unsigned* __restrict__ mx_g) {
  int b = blockIdx.x, n = blockIdx.y, tid = threadIdx.x;
  if (mgt[b * NGT + n] == 0) return;
  int col = b * NGT + n;
  int P = cnts[col];
  if (P > cap) P = cap;
  const unsigned long long* list = lists + (size_t)col * cap;

  const unsigned MN_ID = __float_as_uint(1e30f);  // identity for min
  unsigned loc_mn = MN_ID, loc_mx = 0u;           // am_max >= 0 -> uint order

  if (P >= 10) {
    // All 10 winners are positive => in_gts guaranteed.
    unsigned long long top[10];
#pragma unroll
    for (int j = 0; j < 10; j++) top[j] = 0ull;
    for (int i = tid; i < P; i += 64) {
      unsigned long long key = list[i];
#pragma unroll
      for (int j = 0; j < 10; j++) {
        if (key > top[j]) { unsigned long long t = top[j]; top[j] = key; key = t; }
      }
    }
    for (int r = 0; r < 10; r++) {
      unsigned long long g = top[0];
#pragma unroll
      for (int off = 32; off >= 1; off >>= 1) {
        unsigned long long o = __shfl_xor(g, off, 64);
        g = (o > g) ? o : g;
      }
      // all lanes hold g; unique keys -> exactly one lane pops
      if (top[0] == g) {
#pragma unroll
        for (int j = 0; j < 9; j++) top[j] = top[j + 1];
        top[9] = 0ull;
      }
      if (tid == r) {
        int a = (int)(0xFFFFFFFFu - (unsigned)(g & 0xFFFFFFFFull));
        atomicOr(&fg_mask[(size_t)b * A_N + a], 1);
        unsigned u = __float_as_uint(am_max_g[(size_t)b * A_N + a]);
        loc_mn = (u < loc_mn) ? u : loc_mn;
        loc_mx = (u > loc_mx) ? u : loc_mx;
      }
    }
    // fold the 10 lanes' contributions (others hold identities)
#pragma unroll
    for (int off = 32; off >= 1; off >>= 1) {
      unsigned o1 = __shfl_xor(loc_mn, off, 64);
      loc_mn = (o1 < loc_mn) ? o1 : loc_mn;
      unsigned o2 = __shfl_xor(loc_mx, off, 64);
      loc_mx = (o2 > loc_mx) ? o2 : loc_mx;
    }
    if (tid == 0) {
      if (loc_mn != MN_ID) atomicMin(&mn_g[b], loc_mn);
      if (loc_mx != 0u || loc_mn != MN_ID) atomicMax(&mx_g[b], loc_mx);
    }
  } else if (tid == 0) {
    // P < 10: positives all win; then walk smallest-index zero-valued anchors.
    int pos_a[9];
    for (int i = 0; i < P; i++) {
      int a = (int)(0xFFFFFFFFu - (unsigned)(list[i] & 0xFFFFFFFFull));
      pos_a[i] = a;
      atomicOr(&fg_mask[(size_t)b * A_N + a], 1);
      unsigned u = __float_as_uint(am_max_g[(size_t)b * A_N + a]);
      loc_mn = (u < loc_mn) ? u : loc_mn;
      loc_mx = (u > loc_mx) ? u : loc_mx;
    }
    float4 gb = ((const float4*)gt_b)[b * NGT + n];
    int need = 10 - P;
    int a = 0;
    while (need > 0 && a < A_N) {
      bool is_pos = false;
      for (int i = 0; i < P; i++) is_pos |= (pos_a[i] == a);
      if (!is_pos) {
        // zero-valued winner: consumes a slot regardless; fg only if in_gts
        float2 ap = ((const float2*)anc)[a];
        float mn = fminf(fminf(ap.x - gb.x, ap.y - gb.y),
                         fminf(gb.z - ap.x, gb.w - ap.y));
        if (mn > 0.0f) {
          atomicOr(&fg_mask[(size_t)b * A_N + a], 1);
          unsigned u = __float_as_uint(am_max_g[(size_t)b * A_N + a]);
          loc_mn = (u < loc_mn) ? u : loc_mn;
          loc_mx = (u > loc_mx) ? u : loc_mx;
        }
        need--;
      }
      a++;
    }
    if (loc_mn != MN_ID) atomicMin(&mn_g[b], loc_mn);
    if (loc_mx != 0u || loc_mn != MN_ID) atomicMax(&mx_g[b], loc_mx);
  }
}

// ---------------------------------------------------------------------------
// Output: t_labels, t_bboxes, fg per anchor; then the 80-class score block
// written contiguously (80 KB / block, coalesced float4) from LDS-staged
// cls/norm.
// ---------------------------------------------------------------------------
__global__ __launch_bounds__(256) void k_out_fused(
    const int* __restrict__ gt_l, const float* __restrict__ gt_b,
    const int* __restrict__ fg_mask, const int* __restrict__ gt_idx,
    const float* __restrict__ am_max_g, const unsigned* __restrict__ mn_g,
    const unsigned* __restrict__ mx_g, float* __restrict__ out) {
  int b = blockIdx.y;
  int tid = threadIdx.x;
  int a0 = blockIdx.x * 256;
  int a = a0 + tid;

  __shared__ int cls_s[256];
  __shared__ float norm_s[256];

  if (a < A_N) {
    size_t i = (size_t)b * A_N + a;
    bool fg = fg_mask[i] != 0;
    int bi = gt_idx[i];
    float amx = am_max_g[i];
    float mn = __uint_as_float(mn_g[b]);
    float mx = __uint_as_float(mx_g[b]);
    float norm = (amx - mn) / ((mx - mn) + 1e-9f);
    int lab = gt_l[b * NGT + bi];

    out[i] = fg ? (float)lab : (float)NC;  // t_labels
    float4 bb = fg ? ((const float4*)gt_b)[b * NGT + bi]
                   : make_float4(0.f, 0.f, 0.f, 0.f);
    ((float4*)(out + BA))[i] = bb;               // t_bboxes
    out[(size_t)85 * BA + i] = fg ? 1.0f : 0.0f; // fg
    cls_s[tid] = fg ? lab : -1;
    norm_s[tid] = fg ? norm : 0.0f;
  } else {
    cls_s[tid] = -1;
    norm_s[tid] = 0.0f;
  }
  __syncthreads();

  int nA = A_N - a0;
  if (nA > 256) nA = 256;
  float4* dst = (float4*)(out + (size_t)5 * BA + ((size_t)b * A_N + a0) * NC);
  int nvec = nA * (NC / 4);
  for (int t = tid; t < nvec; t += 256) {
    int al = t / (NC / 4);
    int c0 = (t - al * (NC / 4)) * 4;
    int cls = cls_s[al];
    float nv = norm_s[al];
    float4 r;
    r.x = (c0 == cls) ? nv : 0.0f;
    r.y = (c0 + 1 == cls) ? nv : 0.0f;
    r.z = (c0 + 2 == cls) ? nv : 0.0f;
    r.w = (c0 + 3 == cls) ? nv : 0.0f;
    dst[t] = r;
  }
}

extern "C" void kernel_launch(void* const* d_in, const int* in_sizes, int n_in,
                              void* d_out, int out_size, void* d_ws,
                              size_t ws_size, hipStream_t stream) {
  const float* pd_s = (const float*)d_in[0];   // (B, A, 80)
  const float* pd_b = (const float*)d_in[1];   // (B, A, 4)
  const float* anc  = (const float*)d_in[2];   // (A, 2)
  const int*   gt_l = (const int*)d_in[3];     // (B, 64, 1)
  const float* gt_b = (const float*)d_in[4];   // (B, 64, 4)
  const int*   mgt  = (const int*)d_in[5];     // (B, 64, 1)

  float* out = (float*)d_out;
  char* ws = (char*)d_ws;

  // Small buffers at the end; per-column lists take the rest (cap per column).
  const size_t SMALL = (size_t)BA * 4;
  size_t small_bytes = 3 * SMALL + (size_t)NCOL * 4 + 256;
  size_t avail = (ws_size > small_bytes) ? (ws_size - small_bytes) : 0;
  int cap = (int)(avail / ((size_t)NCOL * 8));
  if (cap > 4096) cap = 4096;  // max in_gts anchors/col is ~800 with this data
  if (cap < 1) cap = 1;

  unsigned long long* lists = (unsigned long long*)ws;
  char* sb = ws + (size_t)NCOL * 8 * cap;
  int*      fg_mask  = (int*)sb;
  int*      gt_idx   = (int*)(sb + SMALL);
  float*    am_max_g = (float*)(sb + 2 * SMALL);
  int*      cnts     = (int*)(sb + 3 * SMALL);
  unsigned* mn_g     = (unsigned*)(sb + 3 * SMALL + (size_t)NCOL * 4);
  unsigned* mx_g     = mn_g + B_N;

  dim3 g2((A_N + 255) / 256, B_N);
  k_init_all<<<(BA + 255) / 256, 256, 0, stream>>>(fg_mask, cnts, mn_g, mx_g);
  k_pairs<<<g2, 256, 0, stream>>>(pd_s, pd_b, anc, gt_l, gt_b, mgt, lists,
                                  cnts, cap, gt_idx, am_max_g);
  k_topk_sparse<<<dim3(B_N, NGT), 64, 0, stream>>>(lists, cnts, cap, mgt, anc,
                                                   gt_b, am_max_g, fg_mask,
                                                   mn_g, mx_g);
  k_out_fused<<<g2, 256, 0, stream>>>(gt_l, gt_b, fg_mask, gt_idx, am_max_g,
                                      mn_g, mx_g, out);
}